// Round 3
// baseline (170.843 us; speedup 1.0000x reference)
//
#include <hip/hip_runtime.h>
#include <hip/hip_bf16.h>

// Problem constants: B=8, L=1024, D=1024, H=16, K=64
// Reference (bug reproduced): no softmax => linear attention:
//   out = ( Q @ (K^T V / 8) ) @ Wout + bout, per (b,h) 64x64 inner matrix.

typedef __attribute__((ext_vector_type(8))) short short8;
typedef __attribute__((ext_vector_type(4))) float f32x4;

static __device__ __forceinline__ short f2bf(float f) {
  __hip_bfloat16 h = __float2bfloat16(f);
  return __builtin_bit_cast(short, h);
}
static __device__ __forceinline__ float bf2f(short s) {
  unsigned int u = ((unsigned int)(unsigned short)s) << 16;
  return __builtin_bit_cast(float, u);
}

#define GLOAD16(src, dst)                                        \
  __builtin_amdgcn_global_load_lds(                              \
      (const __attribute__((address_space(1))) void*)(src),      \
      (__attribute__((address_space(3))) void*)(dst), 16, 0, 0)
#define BAR() __builtin_amdgcn_s_barrier()
#define SCHED() __builtin_amdgcn_sched_barrier(0)
#define WAIT_LGKM0() asm volatile("s_waitcnt lgkmcnt(0)" ::: "memory")
#define WAIT_VM6() asm volatile("s_waitcnt vmcnt(6)" ::: "memory")

// ---------------- cast fp32 -> bf16 (vectorized, exact-size grid) --------
__global__ __launch_bounds__(256) void cast_f32_bf16_kernel(
    const float* __restrict__ in, __hip_bfloat16* __restrict__ out) {
  size_t i = ((size_t)blockIdx.x * 256 + threadIdx.x) * 8;
  float4 v0 = *(const float4*)(in + i);
  float4 v1 = *(const float4*)(in + i + 4);
  short8 o;
  o[0] = f2bf(v0.x); o[1] = f2bf(v0.y); o[2] = f2bf(v0.z); o[3] = f2bf(v0.w);
  o[4] = f2bf(v1.x); o[5] = f2bf(v1.y); o[6] = f2bf(v1.z); o[7] = f2bf(v1.w);
  *(short8*)((__hip_bfloat16*)out + i) = o;
}

// ---------------- transpose + cast fp32 (R x C) -> bf16 (C x R) ----------
__global__ __launch_bounds__(256) void transpose_cast_kernel(
    const float* __restrict__ in, __hip_bfloat16* __restrict__ out, int R, int C) {
  __shared__ float tile[32][33];
  int c0 = blockIdx.x * 32, r0 = blockIdx.y * 32;
  int tx = threadIdx.x & 31;
  int ty = threadIdx.x >> 5;  // 0..7
#pragma unroll
  for (int i = 0; i < 4; ++i)
    tile[ty + i * 8][tx] = in[(size_t)(r0 + ty + i * 8) * C + c0 + tx];
  __syncthreads();
#pragma unroll
  for (int i = 0; i < 4; ++i)
    out[(size_t)(c0 + ty + i * 8) * R + r0 + tx] =
        __float2bfloat16(tile[tx][ty + i * 8]);
}

// =============== 256x256 8-phase bf16 MFMA GEMM (T1+T3+T4+T5) ============
// C(MxN) = A(MxKd) @ Bt(NxKd)^T + bias.  BK=64, 512 thr = 8 waves (2Mx4N).
// LDS: A,B each 2buf x 2half x [128 rows][64 K] bf16, stored as 16x32-bf16
// subtiles (1024B) with a bijective lane permutation so every fragment
// ds_read_b128 instruction covers one full contiguous 1KB subtile
// (conflict-free, T2-equivalent).  One half-tile staged per phase via
// global_load_lds (linear LDS dest, pre-permuted global src, m173).
// vmcnt(6) only at phases 4 and 8 (T4).  setprio around MFMA (T5).
static __device__ __forceinline__ void store_out(__hip_bfloat16* p, float v) {
  *p = __float2bfloat16(v);
}
static __device__ __forceinline__ void store_out(float* p, float v) { *p = v; }

template <typename OutT>
__global__ __launch_bounds__(512, 2) void gemm8p_kernel(
    const __hip_bfloat16* __restrict__ A, const __hip_bfloat16* __restrict__ Bt,
    const float* __restrict__ bias, OutT* __restrict__ C,
    int M, int N, int Kd, int ntn) {
  // granule = 8 bf16 = 16B. buf = 2048 granules (32KB). half = 1024.
  __shared__ short8 sA[2][2048];
  __shared__ short8 sB[2][2048];

  const int t = threadIdx.x;
  const int w = t >> 6, lane = t & 63;
  const int wm = w >> 2, wn = w & 3;  // 2 x 4 wave grid

  // bijective XCD swizzle (gridDim.x % 8 == 0 for all our launches)
  const int nwg = gridDim.x, cpx = nwg >> 3;
  const int wg = (blockIdx.x & 7) * cpx + (blockIdx.x >> 3);
  const int bm = wg / ntn, bn = wg % ntn;
  const size_t m0 = (size_t)bm * 256, n0 = (size_t)bn * 256;

  // staging decode: instr i stages granule g = i*512 + t of a half-tile.
  // subtile st=g>>6 (sr=st>>1, sc=st&1); within: rr=(g>>2)&15, cc=g&3.
  // global row (in half) = sr*16+rr, kcol = sc*32 + cc*8.
  int srow[2], skc[2];
#pragma unroll
  for (int i = 0; i < 2; ++i) {
    int g = i * 512 + t;
    int st = g >> 6;
    srow[i] = (st >> 1) * 16 + ((g >> 2) & 15);
    skc[i] = (st & 1) * 32 + (g & 3) * 8;
  }
  // fragment-read permutation: granule within subtile
  const int perm = (lane & 15) * 4 + (lane >> 4);

  const int kTiles = Kd >> 6;  // 64-wide K tiles (16 for Kd=1024)
  const int kMask = kTiles - 1;

  f32x4 acc[8][4] = {};
  short8 aF[4][2], bF[4][2];

  // ---- staging helpers (2 x global_load_lds each; wave-uniform LDS dest)
  auto stageA = [&](int buf, int h, int kt) {
#pragma unroll
    for (int i = 0; i < 2; ++i)
      GLOAD16(A + (m0 + h * 128 + srow[i]) * (size_t)Kd + kt * 64 + skc[i],
              &sA[buf][h * 1024 + i * 512 + w * 64]);
  };
  auto stageB = [&](int buf, int h, int kt) {
#pragma unroll
    for (int i = 0; i < 2; ++i)
      GLOAD16(Bt + (n0 + h * 128 + srow[i]) * (size_t)Kd + kt * 64 + skc[i],
              &sB[buf][h * 1024 + i * 512 + w * 64]);
  };
  // ---- fragment reads (each = one ds_read_b128, one 1KB subtile) --------
  auto readA = [&](int buf, int miBase) {
#pragma unroll
    for (int mi = 0; mi < 4; ++mi)
#pragma unroll
      for (int kk = 0; kk < 2; ++kk)
        aF[mi][kk] = sA[buf][wm * 1024 + ((miBase + mi) * 2 + kk) * 64 + perm];
  };
  auto readB = [&](int buf) {
#pragma unroll
    for (int ni = 0; ni < 4; ++ni)
#pragma unroll
      for (int kk = 0; kk < 2; ++kk)
        bF[ni][kk] =
            sB[buf][(wn >> 1) * 1024 + (((wn & 1) * 4 + ni) * 2 + kk) * 64 + perm];
  };
  // ---- 16-MFMA cluster: quadrant (miBase..+3) x (niBase..+1), kk 0..1 ---
  auto mfma16 = [&](int miBase, int niBase) {
    __builtin_amdgcn_s_setprio(1);
#pragma unroll
    for (int kk = 0; kk < 2; ++kk)
#pragma unroll
      for (int ni = 0; ni < 2; ++ni)
#pragma unroll
        for (int mi = 0; mi < 4; ++mi)
          acc[miBase + mi][niBase + ni] = __builtin_amdgcn_mfma_f32_16x16x32_bf16(
              aF[mi][kk], bF[niBase + ni][kk], acc[miBase + mi][niBase + ni],
              0, 0, 0);
    __builtin_amdgcn_s_setprio(0);
  };

  // ---- prologue: tile0 (all 4 halves) + tile1 (B0,B1,A0) = 14 loads ----
  stageA(0, 0, 0); stageA(0, 1, 0); stageB(0, 0, 0); stageB(0, 1, 0);
  stageB(1, 0, 1); stageB(1, 1, 1); stageA(1, 0, 1);
  WAIT_VM6();  // tile0's 8 loads retired
  SCHED();
  BAR();
  SCHED();

  for (int it = 0; it < kTiles / 2; ++it) {
    const int t1 = 2 * it + 1;
    const int t2 = (2 * it + 2) & kMask;  // wrap-around prefetch on last iter
    const int t3 = (2 * it + 3) & kMask;
    // ph1: read B(t)+A(t,mi0-3) from buf0; stage A1(t+1)->buf1
    readB(0); readA(0, 0);
    stageA(1, 1, t1);
    BAR(); SCHED(); WAIT_LGKM0(); SCHED();
    mfma16(0, 0);
    BAR(); SCHED();
    // ph2: stage B0(t+2)->buf0 (B buf0 free since ph1)
    stageB(0, 0, t2);
    BAR(); SCHED();
    mfma16(0, 2);
    BAR(); SCHED();
    // ph3: read A(t,mi4-7); stage B1(t+2)->buf0
    readA(0, 4);
    stageB(0, 1, t2);
    BAR(); SCHED(); WAIT_LGKM0(); SCHED();
    mfma16(4, 0);
    BAR(); SCHED();
    // ph4: stage A0(t+2)->buf0 (A buf0 free after ph3); vmcnt(6) => t+1 landed
    stageA(0, 0, t2);
    WAIT_VM6(); SCHED();
    BAR(); SCHED();
    mfma16(4, 2);
    BAR(); SCHED();
    // ph5: read B(t+1)+A(t+1,mi0-3) from buf1; stage A1(t+2)->buf0
    readB(1); readA(1, 0);
    stageA(0, 1, t2);
    BAR(); SCHED(); WAIT_LGKM0(); SCHED();
    mfma16(0, 0);
    BAR(); SCHED();
    // ph6: stage B0(t+3)->buf1 (B buf1 free since ph5)
    stageB(1, 0, t3);
    BAR(); SCHED();
    mfma16(0, 2);
    BAR(); SCHED();
    // ph7: read A(t+1,mi4-7); stage B1(t+3)->buf1
    readA(1, 4);
    stageB(1, 1, t3);
    BAR(); SCHED(); WAIT_LGKM0(); SCHED();
    mfma16(4, 0);
    BAR(); SCHED();
    // ph8: stage A0(t+3)->buf1; vmcnt(6) => t+2 landed
    stageA(1, 0, t3);
    WAIT_VM6(); SCHED();
    BAR(); SCHED();
    mfma16(4, 2);
    BAR(); SCHED();
  }

  // ---- epilogue: C/D layout col=lane&15, row=(lane>>4)*4+reg ----
  const int lr = lane & 15, kg = lane >> 4;
#pragma unroll
  for (int mi = 0; mi < 8; ++mi) {
    size_t row0 = m0 + wm * 128 + mi * 16 + kg * 4;
#pragma unroll
    for (int ni = 0; ni < 4; ++ni) {
      size_t col = n0 + wn * 64 + ni * 16 + lr;
      float bv = bias[col];
#pragma unroll
      for (int r = 0; r < 4; ++r)
        store_out(&C[(row0 + r) * N + col], acc[mi][ni][r] + bv);
    }
  }
}

// ---------------- Spart[c][b,h] = K_h^T @ V_h over 128 L-rows ------------
__global__ __launch_bounds__(256) void ktv_kernel(
    const __hip_bfloat16* __restrict__ qkv, float* __restrict__ Spart) {
  __shared__ __align__(16) float Ks[64][68];
  __shared__ __align__(16) float Vs[64][68];
  const int bh = blockIdx.x;                 // 0..127
  const int ch = blockIdx.y;                 // 0..7
  const int b = bh >> 4, h = bh & 15;
  const __hip_bfloat16* base = qkv + (size_t)b * 1024 * 3072;
  const int hoff = h * 64;
  const int t = threadIdx.x;
  const int i0 = (t >> 4) * 4;
  const int j0 = (t & 15) * 4;
  const int srow = t >> 2;
  const int sg0 = t & 3;

  f32x4 acc[4] = {};

  for (int c = 0; c < 2; ++c) {
    int l0 = ch * 128 + c * 64;
#pragma unroll
    for (int rep = 0; rep < 2; ++rep) {
      int g = sg0 + rep * 4;
      const __hip_bfloat16* rowp = base + (size_t)(l0 + srow) * 3072;
      short8 kv = *(const short8*)(rowp + 1024 + hoff + g * 8);
      short8 vv = *(const short8*)(rowp + 2048 + hoff + g * 8);
      f32x4 k0, k1, v0, v1;
#pragma unroll
      for (int e = 0; e < 4; ++e) {
        k0[e] = bf2f(kv[e]); k1[e] = bf2f(kv[4 + e]);
        v0[e] = bf2f(vv[e]); v1[e] = bf2f(vv[4 + e]);
      }
      *(f32x4*)&Ks[srow][g * 8] = k0;
      *(f32x4*)&Ks[srow][g * 8 + 4] = k1;
      *(f32x4*)&Vs[srow][g * 8] = v0;
      *(f32x4*)&Vs[srow][g * 8 + 4] = v1;
    }
    __syncthreads();
#pragma unroll 8
    for (int l = 0; l < 64; ++l) {
      f32x4 kq = *(const f32x4*)&Ks[l][i0];
      f32x4 vq = *(const f32x4*)&Vs[l][j0];
#pragma unroll
      for (int ii = 0; ii < 4; ++ii) acc[ii] += kq[ii] * vq;
    }
    __syncthreads();
  }

  float* Sp = Spart + ((size_t)ch * 128 + bh) * 4096;
#pragma unroll
  for (int ii = 0; ii < 4; ++ii)
#pragma unroll
    for (int jj = 0; jj < 4; ++jj)
      Sp[(i0 + ii) * 64 + j0 + jj] = acc[ii][jj];
}

// ---------------- attn = Q_h @ S[b,h]  -> bf16 (B*L x D, head-interleaved) -
__global__ __launch_bounds__(256) void qs_kernel(
    const __hip_bfloat16* __restrict__ qkv, const float* __restrict__ Spart,
    __hip_bfloat16* __restrict__ attn) {
  __shared__ __align__(16) float Ql[128][68];
  __shared__ __align__(16) float Sl[64][68];
  const int bh = blockIdx.x;
  const int rblk = blockIdx.y;
  const int b = bh >> 4, h = bh & 15;
  const __hip_bfloat16* Qp = qkv + (size_t)b * 1024 * 3072 + h * 64;
  const int r0 = rblk * 128;
  const int t = threadIdx.x;

#pragma unroll
  for (int rep = 0; rep < 4; ++rep) {
    int g = t + rep * 256;
    int row = g >> 3, gg = g & 7;
    short8 qv = *(const short8*)(Qp + (size_t)(r0 + row) * 3072 + gg * 8);
    f32x4 f0, f1;
#pragma unroll
    for (int e = 0; e < 4; ++e) { f0[e] = bf2f(qv[e]); f1[e] = bf2f(qv[4 + e]); }
    *(f32x4*)&Ql[row][gg * 8] = f0;
    *(f32x4*)&Ql[row][gg * 8 + 4] = f1;
  }
#pragma unroll
  for (int rep = 0; rep < 4; ++rep) {
    int g = t + rep * 256;
    int row = g >> 4, gg = g & 15;
    f32x4 s = {};
#pragma unroll
    for (int c = 0; c < 8; ++c)
      s += *(const f32x4*)&Spart[((size_t)c * 128 + bh) * 4096 + row * 64 + gg * 4];
    *(f32x4*)&Sl[row][gg * 4] = s * 0.125f;
  }
  __syncthreads();

  const int rt0 = (t >> 3) * 4;
  const int j0 = (t & 7) * 8;
  f32x4 accA[4] = {}, accB[4] = {};
#pragma unroll 4
  for (int i = 0; i < 64; i += 4) {
    f32x4 q[4], s0[4], s1[4];
#pragma unroll
    for (int rr = 0; rr < 4; ++rr) q[rr] = *(const f32x4*)&Ql[rt0 + rr][i];
#pragma unroll
    for (int ii = 0; ii < 4; ++ii) {
      s0[ii] = *(const f32x4*)&Sl[i + ii][j0];
      s1[ii] = *(const f32x4*)&Sl[i + ii][j0 + 4];
    }
#pragma unroll
    for (int ii = 0; ii < 4; ++ii)
#pragma unroll
      for (int rr = 0; rr < 4; ++rr) {
        accA[rr] += q[rr][ii] * s0[ii];
        accB[rr] += q[rr][ii] * s1[ii];
      }
  }

#pragma unroll
  for (int rr = 0; rr < 4; ++rr) {
    short8 o;
#pragma unroll
    for (int e = 0; e < 4; ++e) {
      o[e] = f2bf(accA[rr][e]);
      o[4 + e] = f2bf(accB[rr][e]);
    }
    *(short8*)(attn + (size_t)(b * 1024 + r0 + rt0 + rr) * 1024 + h * 64 + j0) = o;
  }
}

extern "C" void kernel_launch(void* const* d_in, const int* in_sizes, int n_in,
                              void* d_out, int out_size, void* d_ws, size_t ws_size,
                              hipStream_t stream) {
  const float* x = (const float*)d_in[0];
  const float* w_in = (const float*)d_in[1];
  const float* b_in = (const float*)d_in[2];
  const float* w_out = (const float*)d_in[3];
  const float* b_out = (const float*)d_in[4];
  float* out = (float*)d_out;

  char* ws = (char*)d_ws;
  __hip_bfloat16* x_bf = (__hip_bfloat16*)ws;   ws += (size_t)8192 * 1024 * 2;
  __hip_bfloat16* w_inT = (__hip_bfloat16*)ws;  ws += (size_t)3072 * 1024 * 2;
  __hip_bfloat16* w_outT = (__hip_bfloat16*)ws; ws += (size_t)1024 * 1024 * 2;
  __hip_bfloat16* qkv = (__hip_bfloat16*)ws;    ws += (size_t)8192 * 3072 * 2;
  float* Spart = (float*)ws;                    ws += (size_t)8 * 128 * 64 * 64 * 4;
  __hip_bfloat16* attn = (__hip_bfloat16*)ws;   ws += (size_t)8192 * 1024 * 2;

  cast_f32_bf16_kernel<<<4096, 256, 0, stream>>>(x, x_bf);
  transpose_cast_kernel<<<dim3(96, 32), 256, 0, stream>>>(w_in, w_inT, 1024, 3072);
  transpose_cast_kernel<<<dim3(32, 32), 256, 0, stream>>>(w_out, w_outT, 1024, 1024);

  // GEMM1: qkv = x @ w_in + b_in   (8192 x 3072, Kd=1024) -> bf16
  gemm8p_kernel<__hip_bfloat16><<<32 * 12, 512, 0, stream>>>(
      x_bf, w_inT, b_in, qkv, 8192, 3072, 1024, 12);

  ktv_kernel<<<dim3(128, 8), 256, 0, stream>>>(qkv, Spart);
  qs_kernel<<<dim3(128, 8), 256, 0, stream>>>(qkv, Spart, attn);

  // GEMM4: out = attn @ w_out + b_out  (8192 x 1024, Kd=1024) -> fp32
  gemm8p_kernel<float><<<32 * 4, 512, 0, stream>>>(
      attn, w_outT, b_out, out, 8192, 1024, 1024, 4);
}

// Round 5
// 156.048 us; speedup vs baseline: 1.0948x; 1.0948x over previous
//
#include <hip/hip_runtime.h>
#include <hip/hip_bf16.h>

// Problem constants: B=8, L=1024, D=1024, H=16, K=64
// Reference (bug reproduced): no softmax => linear attention:
//   out_b = Q_b @ U_b + b_out,  U_b[h*64+j, n] = sum_k S_bh[j,k] w_out[h*64+k, n],
//   S_bh = K_h^T V_h / 8.

typedef __attribute__((ext_vector_type(8))) short short8;
typedef __attribute__((ext_vector_type(4))) float f32x4;

static __device__ __forceinline__ short f2bf(float f) {
  __hip_bfloat16 h = __float2bfloat16(f);
  return __builtin_bit_cast(short, h);
}
static __device__ __forceinline__ float bf2f(short s) {
  unsigned int u = ((unsigned int)(unsigned short)s) << 16;
  return __builtin_bit_cast(float, u);
}

#define GLOAD16(src, dst)                                        \
  __builtin_amdgcn_global_load_lds(                              \
      (const __attribute__((address_space(1))) void*)(src),      \
      (__attribute__((address_space(3))) void*)(dst), 16, 0, 0)

// ---------------- cast fp32 -> bf16 (vectorized, exact-size grid) --------
__global__ __launch_bounds__(256) void cast_f32_bf16_kernel(
    const float* __restrict__ in, __hip_bfloat16* __restrict__ out) {
  size_t i = ((size_t)blockIdx.x * 256 + threadIdx.x) * 8;
  float4 v0 = *(const float4*)(in + i);
  float4 v1 = *(const float4*)(in + i + 4);
  short8 o;
  o[0] = f2bf(v0.x); o[1] = f2bf(v0.y); o[2] = f2bf(v0.z); o[3] = f2bf(v0.w);
  o[4] = f2bf(v1.x); o[5] = f2bf(v1.y); o[6] = f2bf(v1.z); o[7] = f2bf(v1.w);
  *(short8*)((__hip_bfloat16*)out + i) = o;
}

// ---------------- transpose + cast fp32 (R x C) -> bf16 (C x R) ----------
__global__ __launch_bounds__(256) void transpose_cast_kernel(
    const float* __restrict__ in, __hip_bfloat16* __restrict__ out, int R, int C) {
  __shared__ float tile[32][33];
  int c0 = blockIdx.x * 32, r0 = blockIdx.y * 32;
  int tx = threadIdx.x & 31;
  int ty = threadIdx.x >> 5;  // 0..7
#pragma unroll
  for (int i = 0; i < 4; ++i)
    tile[ty + i * 8][tx] = in[(size_t)(r0 + ty + i * 8) * C + c0 + tx];
  __syncthreads();
#pragma unroll
  for (int i = 0; i < 4; ++i)
    out[(size_t)(c0 + ty + i * 8) * R + r0 + tx] =
        __float2bfloat16(tile[tx][ty + i * 8]);
}

// ---------------- bf16 MFMA GEMM (m97 structure, compile-time shapes) ----
// C(..xNOUT) = A(stride AS) @ Bt(NxKD)^T + bias.  128x128 tile, BK=32,
// 4 waves (2x2), each wave 64x64 = 4x4 frags of 16x16x32.
// global_load_lds width=16, LINEAR LDS.  XCD-swizzled block mapping.
// blockIdx.y = batch: A += y*1024*AS, C += y*1024*NOUT, Bt += y*BTB.
static __device__ __forceinline__ void store_out(__hip_bfloat16* p, float v) {
  *p = __float2bfloat16(v);
}
static __device__ __forceinline__ void store_out(float* p, float v) { *p = v; }

template <typename OutT, int KD, int AS, int NBN, int NOUT, long BTB>
__global__ __launch_bounds__(256) void gemm_bt_kernel(
    const __hip_bfloat16* __restrict__ A, const __hip_bfloat16* __restrict__ Bt,
    const float* __restrict__ bias, OutT* __restrict__ C) {
  __shared__ __align__(16) __hip_bfloat16 As[128 * 32];
  __shared__ __align__(16) __hip_bfloat16 Bs[128 * 32];

  const int t = threadIdx.x;
  A += (size_t)blockIdx.y * 1024 * AS;
  Bt += (size_t)blockIdx.y * BTB;
  C += (size_t)blockIdx.y * 1024 * NOUT;

  // bijective XCD swizzle (gridDim.x % 8 == 0), bn-fastest within chunk
  const int cpx = gridDim.x >> 3;
  const int wg = (blockIdx.x & 7) * cpx + (blockIdx.x >> 3);
  const int bm = wg / NBN, bn = wg % NBN;
  const int m0 = bm * 128, n0 = bn * 128;

  const int w = t >> 6, lane = t & 63;
  const int wr = w >> 1, wc = w & 1;
  const int lr = lane & 15, kg = lane >> 4;

  // staging granules (8 bf16 = 16B); tile = 512 granules; wave w covers
  // [w*128, w*128+128) in two 64-lane instructions.
  const int g0 = w * 128 + lane;
  const int g1 = g0 + 64;
  const __hip_bfloat16* srcA0 = A + (size_t)(m0 + (g0 >> 2)) * AS + (g0 & 3) * 8;
  const __hip_bfloat16* srcA1 = A + (size_t)(m0 + (g1 >> 2)) * AS + (g1 & 3) * 8;
  const __hip_bfloat16* srcB0 = Bt + (size_t)(n0 + (g0 >> 2)) * KD + (g0 & 3) * 8;
  const __hip_bfloat16* srcB1 = Bt + (size_t)(n0 + (g1 >> 2)) * KD + (g1 & 3) * 8;
  __hip_bfloat16* ldsA0 = As + (size_t)(w * 128) * 8;
  __hip_bfloat16* ldsA1 = As + (size_t)(w * 128 + 64) * 8;
  __hip_bfloat16* ldsB0 = Bs + (size_t)(w * 128) * 8;
  __hip_bfloat16* ldsB1 = Bs + (size_t)(w * 128 + 64) * 8;

  f32x4 acc[4][4] = {};

#pragma unroll 1
  for (int kt = 0; kt < KD / 32; ++kt) {
    GLOAD16(srcA0, ldsA0);
    GLOAD16(srcA1, ldsA1);
    GLOAD16(srcB0, ldsB0);
    GLOAD16(srcB1, ldsB1);
    srcA0 += 32; srcA1 += 32; srcB0 += 32; srcB1 += 32;
    __syncthreads();

    short8 af[4], bfv[4];
#pragma unroll
    for (int mi = 0; mi < 4; ++mi)
      af[mi] = *(const short8*)&As[(wr * 64 + mi * 16 + lr) * 32 + kg * 8];
#pragma unroll
    for (int ni = 0; ni < 4; ++ni)
      bfv[ni] = *(const short8*)&Bs[(wc * 64 + ni * 16 + lr) * 32 + kg * 8];
#pragma unroll
    for (int mi = 0; mi < 4; ++mi)
#pragma unroll
      for (int ni = 0; ni < 4; ++ni)
        acc[mi][ni] = __builtin_amdgcn_mfma_f32_16x16x32_bf16(
            af[mi], bfv[ni], acc[mi][ni], 0, 0, 0);
    __syncthreads();
  }

  // C/D layout (m89-verified): col = lane&15, row = (lane>>4)*4 + reg
#pragma unroll
  for (int mi = 0; mi < 4; ++mi) {
    int row0 = m0 + wr * 64 + mi * 16 + kg * 4;
#pragma unroll
    for (int ni = 0; ni < 4; ++ni) {
      int col = n0 + wc * 64 + ni * 16 + lr;
      float bv = bias[col];
#pragma unroll
      for (int r = 0; r < 4; ++r)
        store_out(&C[(size_t)(row0 + r) * NOUT + col], acc[mi][ni][r] + bv);
    }
  }
}

// ---------------- Spart[c][b,h] = K_h^T @ V_h over 128 L-rows ------------
__global__ __launch_bounds__(256) void ktv_kernel(
    const __hip_bfloat16* __restrict__ qkv, float* __restrict__ Spart) {
  __shared__ __align__(16) float Ks[64][68];
  __shared__ __align__(16) float Vs[64][68];
  const int bh = blockIdx.x;                 // 0..127
  const int ch = blockIdx.y;                 // 0..7
  const int b = bh >> 4, h = bh & 15;
  const __hip_bfloat16* base = qkv + (size_t)b * 1024 * 3072;
  const int hoff = h * 64;
  const int t = threadIdx.x;
  const int i0 = (t >> 4) * 4;
  const int j0 = (t & 15) * 4;
  const int srow = t >> 2;
  const int sg0 = t & 3;

  f32x4 acc[4] = {};

  for (int c = 0; c < 2; ++c) {
    int l0 = ch * 128 + c * 64;
#pragma unroll
    for (int rep = 0; rep < 2; ++rep) {
      int g = sg0 + rep * 4;
      const __hip_bfloat16* rowp = base + (size_t)(l0 + srow) * 3072;
      short8 kv = *(const short8*)(rowp + 1024 + hoff + g * 8);
      short8 vv = *(const short8*)(rowp + 2048 + hoff + g * 8);
      f32x4 k0, k1, v0, v1;
#pragma unroll
      for (int e = 0; e < 4; ++e) {
        k0[e] = bf2f(kv[e]); k1[e] = bf2f(kv[4 + e]);
        v0[e] = bf2f(vv[e]); v1[e] = bf2f(vv[4 + e]);
      }
      *(f32x4*)&Ks[srow][g * 8] = k0;
      *(f32x4*)&Ks[srow][g * 8 + 4] = k1;
      *(f32x4*)&Vs[srow][g * 8] = v0;
      *(f32x4*)&Vs[srow][g * 8 + 4] = v1;
    }
    __syncthreads();
#pragma unroll 8
    for (int l = 0; l < 64; ++l) {
      f32x4 kq = *(const f32x4*)&Ks[l][i0];
      f32x4 vq = *(const f32x4*)&Vs[l][j0];
#pragma unroll
      for (int ii = 0; ii < 4; ++ii) acc[ii] += kq[ii] * vq;
    }
    __syncthreads();
  }

  float* Sp = Spart + ((size_t)ch * 128 + bh) * 4096;
#pragma unroll
  for (int ii = 0; ii < 4; ++ii)
#pragma unroll
    for (int jj = 0; jj < 4; ++jj)
      Sp[(i0 + ii) * 64 + j0 + jj] = acc[ii][jj];
}

// ---------------- Ut_b[n][h*64+j] = sum_k (S_bh[j][k]/8) w_outT[n][h*64+k]
// One block per (b,h); 8 waves; wave w handles n-rows [w*128, w*128+128).
// MFMA: A = w_outT slice (global, K-contig), Bt = S_bh (LDS bf16).
__global__ __launch_bounds__(512) void ut_kernel(
    const float* __restrict__ Spart, const __hip_bfloat16* __restrict__ w_outT,
    __hip_bfloat16* __restrict__ Ut) {
  __shared__ __align__(16) __hip_bfloat16 Sl[64][72];  // +8 pad
  const int bh = blockIdx.x;
  const int b = bh >> 4, h = bh & 15;
  const int t = threadIdx.x, w = t >> 6, lane = t & 63;
  const int lr = lane & 15, kg = lane >> 4;

  // stage S_bh: sum 8 partials, scale 1/8, cast bf16
#pragma unroll
  for (int rep = 0; rep < 2; ++rep) {
    int e4 = t + rep * 512;          // f32x4 granule 0..1023
    int row = e4 >> 4, c4 = e4 & 15;
    f32x4 s = {};
#pragma unroll
    for (int c = 0; c < 8; ++c)
      s += *(const f32x4*)&Spart[((size_t)c * 128 + bh) * 4096 + row * 64 + c4 * 4];
    s *= 0.125f;
    __hip_bfloat16* p = &Sl[row][c4 * 4];
    p[0] = __float2bfloat16(s[0]); p[1] = __float2bfloat16(s[1]);
    p[2] = __float2bfloat16(s[2]); p[3] = __float2bfloat16(s[3]);
  }
  __syncthreads();

  const __hip_bfloat16* Ap = w_outT + (size_t)(w * 128 + lr) * 1024 + h * 64 + kg * 8;
  short8 bF[4][2];
#pragma unroll
  for (int ni = 0; ni < 4; ++ni)
#pragma unroll
    for (int kk = 0; kk < 2; ++kk)
      bF[ni][kk] = *(const short8*)&Sl[ni * 16 + lr][kk * 32 + kg * 8];

  f32x4 acc[8][4] = {};
#pragma unroll
  for (int mi = 0; mi < 8; ++mi) {
#pragma unroll
    for (int kk = 0; kk < 2; ++kk) {
      short8 aF = *(const short8*)(Ap + (size_t)mi * 16 * 1024 + kk * 32);
#pragma unroll
      for (int ni = 0; ni < 4; ++ni)
        acc[mi][ni] = __builtin_amdgcn_mfma_f32_16x16x32_bf16(
            aF, bF[ni][kk], acc[mi][ni], 0, 0, 0);
    }
  }

  __hip_bfloat16* Up = Ut + (size_t)b * 1024 * 1024;
#pragma unroll
  for (int mi = 0; mi < 8; ++mi) {
    int row0 = w * 128 + mi * 16 + kg * 4;
#pragma unroll
    for (int ni = 0; ni < 4; ++ni) {
      int col = h * 64 + ni * 16 + lr;
#pragma unroll
      for (int r = 0; r < 4; ++r)
        Up[(size_t)(row0 + r) * 1024 + col] = __float2bfloat16(acc[mi][ni][r]);
    }
  }
}

extern "C" void kernel_launch(void* const* d_in, const int* in_sizes, int n_in,
                              void* d_out, int out_size, void* d_ws, size_t ws_size,
                              hipStream_t stream) {
  const float* x = (const float*)d_in[0];
  const float* w_in = (const float*)d_in[1];
  const float* b_in = (const float*)d_in[2];
  const float* w_out = (const float*)d_in[3];
  const float* b_out = (const float*)d_in[4];
  float* out = (float*)d_out;

  char* ws = (char*)d_ws;
  __hip_bfloat16* x_bf = (__hip_bfloat16*)ws;   ws += (size_t)8192 * 1024 * 2;
  __hip_bfloat16* w_inT = (__hip_bfloat16*)ws;  ws += (size_t)3072 * 1024 * 2;
  __hip_bfloat16* w_outT = (__hip_bfloat16*)ws; ws += (size_t)1024 * 1024 * 2;
  __hip_bfloat16* qkv = (__hip_bfloat16*)ws;    ws += (size_t)8192 * 3072 * 2;
  float* Spart = (float*)ws;                    ws += (size_t)8 * 128 * 64 * 64 * 4;
  __hip_bfloat16* Ut = (__hip_bfloat16*)ws;     ws += (size_t)8 * 1024 * 1024 * 2;

  cast_f32_bf16_kernel<<<4096, 256, 0, stream>>>(x, x_bf);
  transpose_cast_kernel<<<dim3(96, 32), 256, 0, stream>>>(w_in, w_inT, 1024, 3072);
  transpose_cast_kernel<<<dim3(32, 32), 256, 0, stream>>>(w_out, w_outT, 1024, 1024);

  // GEMM1: qkv = x @ w_in + b_in  (8192 x 3072, KD=1024) -> bf16
  gemm_bt_kernel<__hip_bfloat16, 1024, 1024, 24, 3072, 0>
      <<<dim3(1536, 1), 256, 0, stream>>>(x_bf, w_inT, b_in, qkv);

  // S partials = Kt V per (b,h) over 128-row chunks
  ktv_kernel<<<dim3(128, 8), 256, 0, stream>>>(qkv, Spart);

  // Ut_b = (S_bh/8 @ Wout_h)^T stacked  -> bf16 (8 x 1024 x 1024)
  ut_kernel<<<128, 512, 0, stream>>>(Spart, w_outT, Ut);

  // GEMM4': out_b = Q_b @ U_b + b_out  (8 batched 1024x1024, A stride 3072,
  //         Bt batch stride 1024*1024)
  gemm_bt_kernel<float, 1024, 3072, 8, 1024, 1024 * 1024>
      <<<dim3(64, 8), 256, 0, stream>>>(qkv, Ut, b_out, out);
}